// Round 19
// baseline (215.518 us; speedup 1.0000x reference)
//
#include <hip/hip_runtime.h>

#define D 64
#define BK_SHIFT 8
#define BK_MASK 255
#define SEGCAP 4096
#define ESLICE 4096
#define CAP 16384   // slack + line-align padding (mean padded fill ~10.2K)

typedef __attribute__((ext_vector_type(8))) short short8;   // 8 bf16 = 4 VGPRs
typedef __attribute__((ext_vector_type(4))) float floatx4;  // MFMA C/D

__device__ __forceinline__ ushort f2bf(float f) {     // fp32 -> bf16, RNE
    unsigned u = __float_as_uint(f);
    u += 0x7fffu + ((u >> 16) & 1u);
    return (ushort)(u >> 16);
}
__device__ __forceinline__ float bf2f(ushort h) {
    return __int_as_float(((unsigned)h) << 16);
}

// ---------------- fused: edge route (blocks < eslices) + cast (rest) --------------
// Round-19: LINE-ALIGNED reservations. Each (block,bucket) chunk is rounded up
// to 32 ints (128B) so every bucketed2 cache line has exactly ONE writer block
// (one XCD) -- kills the cross-XCD dirty-line ping-pong + sector RMW of 4B
// scattered placement. Holes stay 0xFFFFFFFF (bucketed2 pre-memset to 0xFF);
// bkreal tracks exact counts for csr's dense srclist scan.
__global__ void cast_route_kernel(const float* __restrict__ x, ushort* __restrict__ xh,
                                  const int* __restrict__ ei, int* __restrict__ bkcur,
                                  int* __restrict__ bkreal,
                                  int* __restrict__ ovn, int* __restrict__ ov,
                                  int* __restrict__ bucketed2,
                                  int n4, int E, int B, int eslices) {
    int bid = blockIdx.x;
    int tid = threadIdx.x;
    if (bid >= eslices) {                    // ---- cast role
        int i = (bid - eslices) * 256 + tid;
        if (i >= n4) return;
        float4 v = ((const float4*)x)[i];
        ushort4 r;
        r.x = f2bf(v.x); r.y = f2bf(v.y); r.z = f2bf(v.z); r.w = f2bf(v.w);
        ((ushort4*)xh)[i] = r;
        return;
    }
    // ---- edge role: LDS hist -> aligned reserve -> place
    __shared__ int h[512];
    __shared__ int gb[512];
    int t2 = tid + 256;
    h[tid] = 0; h[t2] = 0;
    __syncthreads();
    int e0 = bid * ESLICE;
#pragma unroll 4
    for (int it = 0; it < ESLICE / 256; ++it) {      // pass 1: local hist
        int e = e0 + it * 256 + tid;
        if (e < E) atomicAdd(&h[ei[E + e] >> BK_SHIFT], 1);
    }
    __syncthreads();
    if (tid < B && h[tid]) {
        int res = (h[tid] + 31) & ~31;               // 128B-aligned chunk
        gb[tid] = atomicAdd(&bkcur[tid], res);
        atomicAdd(&bkreal[tid], h[tid]);
    } else gb[tid] = 0;
    if (t2 < B && h[t2]) {
        int res = (h[t2] + 31) & ~31;
        gb[t2] = atomicAdd(&bkcur[t2], res);
        atomicAdd(&bkreal[t2], h[t2]);
    } else gb[t2] = 0;
    __syncthreads();
    h[tid] = 0; h[t2] = 0;                           // reuse as cursors
    __syncthreads();
#pragma unroll 4
    for (int it = 0; it < ESLICE / 256; ++it) {      // pass 2: place (dst L2-hot)
        int e = e0 + it * 256 + tid;
        if (e < E) {
            int dst = ei[E + e];
            int key = dst >> BK_SHIFT;
            int src = ei[e];
            int r = atomicAdd(&h[key], 1);
            int pos = gb[key] + r;
            if (pos < CAP) bucketed2[(size_t)key * CAP + pos] = (src << BK_SHIFT) | (dst & BK_MASK);
            else           ov[atomicAdd(ovn, 1)] = e;          // rare overflow
        }
    }
}

// ---------------- B: per-bucket CSR build + RANK-MAJOR degree perm ----------------
// Dense srclist offsets from a block-redundant 512-scan of bkreal (exact counts;
// bkcur now holds PADDED extents). Sentinel entries (v<0 = alignment holes) are
// skipped. perm is rank-major: local descending rank r in bucket k ->
// perm[r*B + k] (compacted for partial last bucket): same-rank nodes of
// adjacent buckets form a group => degree uniformity ACROSS a block's waves.
__global__ void csr_kernel(const int* __restrict__ bucketed2, const int* __restrict__ ei,
                           const int* __restrict__ bkcur, const int* __restrict__ bkreal,
                           const int* __restrict__ ov, const int* __restrict__ ovn_p,
                           int* __restrict__ srclist, int* __restrict__ beg,
                           int* __restrict__ cnt, int* __restrict__ perm, int N, int E) {
    __shared__ int btot[512];
    __shared__ int lcnt[256];
    __shared__ int lbeg[256];
    __shared__ int seg[SEGCAP];
    __shared__ int wsum[4];
    __shared__ int lh[64];
    __shared__ int sfx[64];
    int k = blockIdx.x;
    int Bb = gridDim.x;
    int tid = threadIdx.x;
    int t2 = tid + 256;
    int nd0 = k << BK_SHIFT;
    int nn = min(256, N - nd0);
    int L = N - (Bb - 1) * 256;              // last-bucket size (1..256)
    int ovn = *ovn_p;
    btot[tid] = (tid < Bb) ? bkreal[tid] : 0;
    btot[t2]  = (t2  < Bb) ? bkreal[t2]  : 0;
    __syncthreads();
    for (int i = tid; i < ovn; i += 256)     // rare: add overflow to totals
        atomicAdd(&btot[ei[E + ov[i]] >> BK_SHIFT], 1);
    __syncthreads();
    int nc   = min(bkcur[k], CAP);           // padded extent of my bucket region
    int ecnt = btot[k];                      // real count incl. overflow
    int a = btot[2 * tid], b = btot[2 * tid + 1];
    __syncthreads();
    // exclusive 512-scan of btot -> prefix
    int s = a + b;
    int lane = tid & 63, w = tid >> 6;
    int p = s;
#pragma unroll
    for (int o = 1; o < 64; o <<= 1) {
        int u = __shfl_up(p, o, 64);
        if (lane >= o) p += u;
    }
    if (lane == 63) wsum[w] = p;
    __syncthreads();
    int base = 0;
    for (int ww = 0; ww < w; ++ww) base += wsum[ww];
    int excl = base + p - s;
    btot[2 * tid] = excl;
    btot[2 * tid + 1] = excl + a;
    lcnt[tid] = 0;
    __syncthreads();
    int ebeg = btot[k];                      // dense srclist base of bucket k
    const int* bk = bucketed2 + (size_t)k * CAP;
    for (int i = tid; i < nc; i += 256) {    // degree count (skip sentinels)
        int v = bk[i];
        if (v >= 0) atomicAdd(&lcnt[v & BK_MASK], 1);
    }
    for (int i = tid; i < ovn; i += 256) {   // rare overflow contribution
        int dst = ei[E + ov[i]];
        if ((dst >> BK_SHIFT) == k) atomicAdd(&lcnt[dst & BK_MASK], 1);
    }
    __syncthreads();
    int c = lcnt[tid];
    p = c;
#pragma unroll
    for (int o = 1; o < 64; o <<= 1) {
        int u = __shfl_up(p, o, 64);
        if (lane >= o) p += u;
    }
    if (lane == 63) wsum[w] = p;
    __syncthreads();
    base = 0;
    for (int ww = 0; ww < w; ++ww) base += wsum[ww];
    excl = base + p - c;
    lbeg[tid] = excl;
    lcnt[tid] = 0;                           // reuse as fill cursors
    __syncthreads();
    if (ecnt <= SEGCAP) {
        for (int i = tid; i < nc; i += 256) {
            int v = bk[i];
            if (v >= 0) {
                int key = v & BK_MASK;
                int pos = lbeg[key] + atomicAdd(&lcnt[key], 1);
                seg[pos] = v >> BK_SHIFT;
            }
        }
        for (int i = tid; i < ovn; i += 256) {
            int e = ov[i];
            int dst = ei[E + e];
            if ((dst >> BK_SHIFT) == k) {
                int key = dst & BK_MASK;
                int pos = lbeg[key] + atomicAdd(&lcnt[key], 1);
                seg[pos] = ei[e];
            }
        }
        __syncthreads();
        for (int i = tid; i < ecnt; i += 256)
            srclist[ebeg + i] = seg[i];      // coalesced full-line dump
    } else {                                 // fallback for giant buckets
        for (int i = tid; i < nc; i += 256) {
            int v = bk[i];
            if (v >= 0) {
                int key = v & BK_MASK;
                int pos = lbeg[key] + atomicAdd(&lcnt[key], 1);
                srclist[ebeg + pos] = v >> BK_SHIFT;
            }
        }
        for (int i = tid; i < ovn; i += 256) {
            int e = ov[i];
            int dst = ei[E + e];
            if ((dst >> BK_SHIFT) == k) {
                int key = dst & BK_MASK;
                int pos = lbeg[key] + atomicAdd(&lcnt[key], 1);
                srclist[ebeg + pos] = ei[e];
            }
        }
    }
    __syncthreads();
    int dg = 0;
    if (tid < nn) {
        dg = lcnt[tid];                      // cursor end == degree
        cnt[nd0 + tid] = dg;
        beg[nd0 + tid] = ebeg + lbeg[tid];
    }
    int bin = dg < 63 ? dg : 63;
    if (tid < 64) lh[tid] = 0;
    __syncthreads();
    if (tid < nn) atomicAdd(&lh[bin], 1);
    __syncthreads();
    if (tid < 64) {                          // suffix scan: high bins first
        int cc = lh[tid];
        int pp = cc;
#pragma unroll
        for (int o = 1; o < 64; o <<= 1) {
            int u = __shfl_down(pp, o, 64);
            if (tid + o < 64) pp += u;
        }
        sfx[tid] = pp - cc;
        lh[tid] = 0;                         // reuse as rank cursor
    }
    __syncthreads();
    if (tid < nn) {
        int rank = sfx[bin] + atomicAdd(&lh[bin], 1);   // 0..nn-1 descending
        int pos = (rank < L) ? rank * Bb + k
                             : L * Bb + (rank - L) * (Bb - 1) + k;
        perm[pos] = nd0 + tid;
    }
}

// ---------------- fused SAGE layer: bf16 gather + MFMA combine ----------------
// SAGE IS AT ITS STRUCTURAL FLOOR (~43-47us/layer): 1M random 128B row fetches
// = MSHR/random-granule bound. Evidence: 16 vs 24 waves/CU identical (r10/r12),
// pipelined si issue no change (r17 falsified). Body = round-12 measured best.
// Register-cap rule (r1/8/11 spilled): keep (256,3); tighter caps SPILL.
// Spill tripwire: WRITE ~31MB(fp32)/18.7MB(bf16).

__global__ void __launch_bounds__(256, 3) sage_kernel(
    const ushort* __restrict__ inh,      // bf16 rows [N][64]
    const int* __restrict__ perm,
    const int* __restrict__ beg_, const int* __restrict__ cnt_,
    const int* __restrict__ srclist,
    const float* __restrict__ Wl, const float* __restrict__ bl,
    const float* __restrict__ Wr,
    float* __restrict__ out_f32,         // fp32 out (layer 2) or null
    ushort* __restrict__ out_bf,         // bf16 out (layer 1) or null
    int N, int relu) {
    __shared__ short8 fL[8][64];   // [c*2+s][lane]: B-frag of Wl^T, col-tile c, k-step s
    __shared__ short8 fR[8][64];
    int tid = threadIdx.x;
    int lane = tid & 63;
    {
        int c = tid >> 6;
        int n = lane & 15;
        int q = lane >> 4;
#pragma unroll
        for (int s = 0; s < 2; ++s) {
            const float* pl = Wl + (c * 16 + n) * D + s * 32 + q * 8;
            const float* pr = Wr + (c * 16 + n) * D + s * 32 + q * 8;
            short8 vl, vr;
#pragma unroll
            for (int j = 0; j < 8; ++j) {
                vl[j] = (short)f2bf(pl[j]);
                vr[j] = (short)f2bf(pr[j]);
            }
            fL[c * 2 + s][lane] = vl;
            fR[c * 2 + s][lane] = vr;
        }
    }
    __syncthreads();

    int m = lane & 15;
    int q = lane >> 4;
    float b0 = bl[m], b1 = bl[16 + m], b2 = bl[32 + m], b3 = bl[48 + m];
    int gwave   = blockIdx.x * 4 + (tid >> 6);
    int nwaves  = gridDim.x * 4;
    int ngroups = (N + 15) >> 4;

    for (int g = gwave; g < ngroups; g += nwaves) {
        int base = g * 16;
        bool nv = (base + m) < N;
        int node = nv ? perm[base + m] : 0;
        int beg = nv ? beg_[node] : 0;   // 4 lanes per node share the address
        int deg = nv ? cnt_[node] : 0;

        // wave-max degree (uniform under rank-major perm)
        int md = deg;
        md = max(md, __shfl_xor(md, 1, 64));
        md = max(md, __shfl_xor(md, 2, 64));
        md = max(md, __shfl_xor(md, 4, 64));
        md = max(md, __shfl_xor(md, 8, 64));

        float f0[8], f1[8];
#pragma unroll
        for (int u = 0; u < 8; ++u) { f0[u] = 0.f; f1[u] = 0.f; }

        // batched gather: 4 hops per stage -> 8 parallel row loads in flight
        for (int j = 0; j < md; j += 4) {
            int si0, si1, si2, si3;
            {
                int j0 = j,     i0 = beg + ((j0 < deg) ? j0 : 0);
                int j1 = j + 1, i1 = beg + ((j1 < deg) ? j1 : 0);
                int j2 = j + 2, i2 = beg + ((j2 < deg) ? j2 : 0);
                int j3 = j + 3, i3 = beg + ((j3 < deg) ? j3 : 0);
                si0 = srclist[i0]; si1 = srclist[i1];
                si2 = srclist[i2]; si3 = srclist[i3];
            }
            const ushort* rp0 = inh + (size_t)si0 * D;
            const ushort* rp1 = inh + (size_t)si1 * D;
            const ushort* rp2 = inh + (size_t)si2 * D;
            const ushort* rp3 = inh + (size_t)si3 * D;
            short8 lo0 = *(const short8*)(rp0 + q * 8);
            short8 hi0 = *(const short8*)(rp0 + 32 + q * 8);
            short8 lo1 = *(const short8*)(rp1 + q * 8);
            short8 hi1 = *(const short8*)(rp1 + 32 + q * 8);
            short8 lo2 = *(const short8*)(rp2 + q * 8);
            short8 hi2 = *(const short8*)(rp2 + 32 + q * 8);
            short8 lo3 = *(const short8*)(rp3 + q * 8);
            short8 hi3 = *(const short8*)(rp3 + 32 + q * 8);
            float m0 = (j     < deg) ? 1.f : 0.f;
            float m1 = (j + 1 < deg) ? 1.f : 0.f;
            float m2 = (j + 2 < deg) ? 1.f : 0.f;
            float m3 = (j + 3 < deg) ? 1.f : 0.f;
#pragma unroll
            for (int u = 0; u < 8; ++u) {
                f0[u] = fmaf(m0, bf2f((ushort)lo0[u]), f0[u]);
                f1[u] = fmaf(m0, bf2f((ushort)hi0[u]), f1[u]);
                f0[u] = fmaf(m1, bf2f((ushort)lo1[u]), f0[u]);
                f1[u] = fmaf(m1, bf2f((ushort)hi1[u]), f1[u]);
                f0[u] = fmaf(m2, bf2f((ushort)lo2[u]), f0[u]);
                f1[u] = fmaf(m2, bf2f((ushort)hi2[u]), f1[u]);
                f0[u] = fmaf(m3, bf2f((ushort)lo3[u]), f0[u]);
                f1[u] = fmaf(m3, bf2f((ushort)hi3[u]), f1[u]);
            }
        }

        float scale = (deg > 0) ? 1.0f / (float)deg : 0.0f;
        short8 a0, a1;
#pragma unroll
        for (int u = 0; u < 8; ++u) {
            a0[u] = (short)f2bf(f0[u] * scale);
            a1[u] = (short)f2bf(f1[u] * scale);
        }

        // root rows load directly as A-fragments
        const ushort* rr = inh + (size_t)node * D;
        short8 r0 = *(const short8*)(rr + q * 8);
        short8 r1 = *(const short8*)(rr + 32 + q * 8);

        // output nodes of my 4 rows (q*4 + r)
        int on0 = __shfl(node, q * 4 + 0, 64);
        int on1 = __shfl(node, q * 4 + 1, 64);
        int on2 = __shfl(node, q * 4 + 2, 64);
        int on3 = __shfl(node, q * 4 + 3, 64);
        bool v0 = (base + q * 4 + 0) < N;
        bool v1 = (base + q * 4 + 1) < N;
        bool v2 = (base + q * 4 + 2) < N;
        bool v3 = (base + q * 4 + 3) < N;

#pragma unroll
        for (int c = 0; c < 4; ++c) {
            float bc = (c == 0) ? b0 : (c == 1) ? b1 : (c == 2) ? b2 : b3;
            floatx4 acc = {bc, bc, bc, bc};
            acc = __builtin_amdgcn_mfma_f32_16x16x32_bf16(a0, fL[c * 2 + 0][lane], acc, 0, 0, 0);
            acc = __builtin_amdgcn_mfma_f32_16x16x32_bf16(a1, fL[c * 2 + 1][lane], acc, 0, 0, 0);
            acc = __builtin_amdgcn_mfma_f32_16x16x32_bf16(r0, fR[c * 2 + 0][lane], acc, 0, 0, 0);
            acc = __builtin_amdgcn_mfma_f32_16x16x32_bf16(r1, fR[c * 2 + 1][lane], acc, 0, 0, 0);
            // direct stores: 16 lanes x consecutive m = 32B (bf16) / 64B (fp32)
            // aligned sector-complete chunks -> no RMW, no LDS staging.
#pragma unroll
            for (int r = 0; r < 4; ++r) {
                float v = acc[r];
                if (relu) v = fmaxf(v, 0.f);
                int onr = (r == 0) ? on0 : (r == 1) ? on1 : (r == 2) ? on2 : on3;
                bool vr = (r == 0) ? v0 : (r == 1) ? v1 : (r == 2) ? v2 : v3;
                if (vr) {
                    size_t off = (size_t)onr * D + c * 16 + m;
                    if (out_bf) out_bf[off] = f2bf(v);
                    else        out_f32[off] = v;
                }
            }
        }
    }
}

extern "C" void kernel_launch(void* const* d_in, const int* in_sizes, int n_in,
                              void* d_out, int out_size, void* d_ws, size_t ws_size,
                              hipStream_t stream) {
    const float* x   = (const float*)d_in[0];
    const int*   ei  = (const int*)d_in[1];
    const float* W1l = (const float*)d_in[2];
    const float* b1l = (const float*)d_in[3];
    const float* W1r = (const float*)d_in[4];
    const float* W2l = (const float*)d_in[5];
    const float* b2l = (const float*)d_in[6];
    const float* W2r = (const float*)d_in[7];
    float* out = (float*)d_out;

    int N = in_sizes[0] / D;   // 100000
    int E = in_sizes[1] / 2;   // 1000000
    int B = (N + BK_MASK) >> BK_SHIFT;   // 391 buckets
    int eslices = (E + ESLICE - 1) / ESLICE;   // 245

    char* ws = (char*)d_ws;
    // Layout (ints unless noted):
    //   xh  bf16 N*D      hh bf16 N*D      srclist E+64
    //   beg N   cnt N   perm N
    //   bkcur 512 + bkreal 512 + ovn 1 + pad 3  (one zero-memset, 1028 ints)
    //   ov E                 (overflow edge indices, rare-path)
    //   bucketed2 B*CAP      (line-aligned bucket chunks, 0xFF-memset, 25.6MB)
    ushort* xh = (ushort*)ws;
    ushort* hh = xh + (size_t)N * D;
    int*   srclist  = (int*)(ws + (size_t)2 * N * D * 2); // E ints + 64 slack
    int*   beg      = srclist + E + 64;                   // N ints
    int*   cnt      = beg + N;                            // N ints
    int*   perm     = cnt + N;                            // N ints
    int*   bkcur    = perm + N;                           // 512 ints (memset 0)
    int*   bkreal   = bkcur + 512;                        // 512 ints (memset 0)
    int*   ovn      = bkreal + 512;                       // 1 int (memset 0)
    int*   ov       = ovn + 4;                            // E ints
    int*   bucketed2 = ov + E;                            // B*CAP ints (memset 0xFF)

    (void)hipMemsetAsync(bkcur, 0, (512 + 512 + 4) * sizeof(int), stream);
    (void)hipMemsetAsync(bucketed2, 0xFF, (size_t)B * CAP * sizeof(int), stream);

    int n4 = N * D / 4;
    int castb = (n4 + 255) / 256;
    cast_route_kernel<<<eslices + castb, 256, 0, stream>>>(x, xh, ei, bkcur, bkreal,
                                                           ovn, ov, bucketed2,
                                                           n4, E, B, eslices);
    csr_kernel<<<B, 256, 0, stream>>>(bucketed2, ei, bkcur, bkreal, ov, ovn,
                                      srclist, beg, cnt, perm, N, E);

    int ngroups = (N + 15) / 16;              // 6250
    int sblocks = (ngroups + 3) / 4;          // 1 group per wave, HW backfill
    // layer 1: hh(bf16) = relu(mean_agg(xh)@W1l^T + b1l + xh@W1r^T)
    sage_kernel<<<sblocks, 256, 0, stream>>>(xh, perm, beg, cnt, srclist,
                                             W1l, b1l, W1r, nullptr, hh, N, 1);
    // layer 2: out(fp32) = mean_agg(hh)@W2l^T + b2l + hh@W2r^T
    sage_kernel<<<sblocks, 256, 0, stream>>>(hh, perm, beg, cnt, srclist,
                                             W2l, b2l, W2r, out, nullptr, N, 0);
}

// Round 20
// 196.883 us; speedup vs baseline: 1.0946x; 1.0946x over previous
//
#include <hip/hip_runtime.h>

#define D 64
#define BK_SHIFT 8
#define BK_MASK 255
#define SEGCAP 4096
#define ESLICE 4096
#define CAP 8192   // slack-strided bucket capacity (mean fill 2560; 30 sigma)

typedef __attribute__((ext_vector_type(8))) short short8;   // 8 bf16 = 4 VGPRs
typedef __attribute__((ext_vector_type(4))) float floatx4;  // MFMA C/D

__device__ __forceinline__ ushort f2bf(float f) {     // fp32 -> bf16, RNE
    unsigned u = __float_as_uint(f);
    u += 0x7fffu + ((u >> 16) & 1u);
    return (ushort)(u >> 16);
}
__device__ __forceinline__ float bf2f(ushort h) {
    return __int_as_float(((unsigned)h) << 16);
}

// ---------------- fused: edge route (blocks < eslices) + cast (rest) --------------
// Round-15 structure (measured best, 199.6us total): slack-strided buckets,
// no count pass, no pre-memset of bucketed2 (round-19's line-aligned variant
// with 25.6MB 0xFF memset REGRESSED to 215us -- do not reintroduce).
__global__ void cast_route_kernel(const float* __restrict__ x, ushort* __restrict__ xh,
                                  const int* __restrict__ ei, int* __restrict__ bkcur,
                                  int* __restrict__ ovn, int* __restrict__ ov,
                                  int* __restrict__ bucketed2,
                                  int n4, int E, int B, int eslices) {
    int bid = blockIdx.x;
    int tid = threadIdx.x;
    if (bid >= eslices) {                    // ---- cast role
        int i = (bid - eslices) * 256 + tid;
        if (i >= n4) return;
        float4 v = ((const float4*)x)[i];
        ushort4 r;
        r.x = f2bf(v.x); r.y = f2bf(v.y); r.z = f2bf(v.z); r.w = f2bf(v.w);
        ((ushort4*)xh)[i] = r;
        return;
    }
    // ---- edge role: LDS hist -> reserve -> place
    __shared__ int h[512];
    __shared__ int gb[512];
    int t2 = tid + 256;
    h[tid] = 0; h[t2] = 0;
    __syncthreads();
    int e0 = bid * ESLICE;
#pragma unroll 4
    for (int it = 0; it < ESLICE / 256; ++it) {      // pass 1: local hist
        int e = e0 + it * 256 + tid;
        if (e < E) atomicAdd(&h[ei[E + e] >> BK_SHIFT], 1);
    }
    __syncthreads();
    gb[tid] = (tid < B && h[tid]) ? atomicAdd(&bkcur[tid], h[tid]) : 0;
    gb[t2]  = (t2  < B && h[t2])  ? atomicAdd(&bkcur[t2],  h[t2])  : 0;
    __syncthreads();
    h[tid] = 0; h[t2] = 0;                           // reuse as cursors
    __syncthreads();
#pragma unroll 4
    for (int it = 0; it < ESLICE / 256; ++it) {      // pass 2: place (dst L2-hot)
        int e = e0 + it * 256 + tid;
        if (e < E) {
            int dst = ei[E + e];
            int key = dst >> BK_SHIFT;
            int src = ei[e];
            int r = atomicAdd(&h[key], 1);
            int pos = gb[key] + r;
            if (pos < CAP) bucketed2[(size_t)key * CAP + pos] = (src << BK_SHIFT) | (dst & BK_MASK);
            else           ov[atomicAdd(ovn, 1)] = e;          // rare overflow
        }
    }
}

// ---------------- B: per-bucket CSR build + RANK-MAJOR degree perm ----------------
// Round-20: 512 THREADS/BLOCK (buckets unchanged at 256 nodes -- round-18's
// bucket split poisoned route; this halves csr's per-entry loop trip counts
// 10->5 without touching route). Dense srclist offsets via block-redundant
// 512-scan of clamped bkcur (+ overflow). perm rank-major: local descending
// rank r in bucket k -> perm[r*B + k] (compacted partial last bucket).
__global__ void csr_kernel(const int* __restrict__ bucketed2, const int* __restrict__ ei,
                           const int* __restrict__ bkcur, const int* __restrict__ ov,
                           const int* __restrict__ ovn_p,
                           int* __restrict__ srclist, int* __restrict__ beg,
                           int* __restrict__ cnt, int* __restrict__ perm, int N, int E) {
    __shared__ int btot[512];
    __shared__ int lcnt[256];
    __shared__ int lbeg[256];
    __shared__ int seg[SEGCAP];
    __shared__ int wsum[8];
    __shared__ int lh[64];
    __shared__ int sfx[64];
    int k = blockIdx.x;
    int Bb = gridDim.x;
    int tid = threadIdx.x;                   // 0..511
    int nd0 = k << BK_SHIFT;
    int nn = min(256, N - nd0);
    int L = N - (Bb - 1) * 256;              // last-bucket size (1..256)
    int ovn = *ovn_p;
    btot[tid] = (tid < Bb) ? min(bkcur[tid], CAP) : 0;
    __syncthreads();
    for (int i = tid; i < ovn; i += 512)     // rare: add overflow to totals
        atomicAdd(&btot[ei[E + ov[i]] >> BK_SHIFT], 1);
    __syncthreads();
    int nc   = min(bkcur[k], CAP);           // entries in my bucket region
    int ecnt = btot[k];                      // incl. overflow
    int a = btot[tid];                       // 1 elem/thread (512-wide)
    __syncthreads();
    // exclusive 512-scan of btot (8 waves)
    int lane = tid & 63, w = tid >> 6;
    int p = a;
#pragma unroll
    for (int o = 1; o < 64; o <<= 1) {
        int u = __shfl_up(p, o, 64);
        if (lane >= o) p += u;
    }
    if (lane == 63) wsum[w] = p;
    __syncthreads();
    int base = 0;
    for (int ww = 0; ww < w; ++ww) base += wsum[ww];
    btot[tid] = base + p - a;                // exclusive prefix
    if (tid < 256) lcnt[tid] = 0;
    __syncthreads();
    int ebeg = btot[k];                      // dense srclist base of bucket k
    const int* bk = bucketed2 + (size_t)k * CAP;
    for (int i = tid; i < nc; i += 512)      // degree count
        atomicAdd(&lcnt[bk[i] & BK_MASK], 1);
    for (int i = tid; i < ovn; i += 512) {   // rare overflow contribution
        int dst = ei[E + ov[i]];
        if ((dst >> BK_SHIFT) == k) atomicAdd(&lcnt[dst & BK_MASK], 1);
    }
    __syncthreads();
    // exclusive 256-scan of lcnt (first 4 waves)
    int c = (tid < 256) ? lcnt[tid] : 0;
    p = c;
#pragma unroll
    for (int o = 1; o < 64; o <<= 1) {
        int u = __shfl_up(p, o, 64);
        if (lane >= o) p += u;
    }
    if (lane == 63 && tid < 256) wsum[w] = p;
    __syncthreads();
    if (tid < 256) {
        base = 0;
        for (int ww = 0; ww < w; ++ww) base += wsum[ww];
        lbeg[tid] = base + p - c;
        lcnt[tid] = 0;                       // reuse as fill cursors
    }
    __syncthreads();
    if (ecnt <= SEGCAP) {
        for (int i = tid; i < nc; i += 512) {
            int v = bk[i];
            int key = v & BK_MASK;
            int pos = lbeg[key] + atomicAdd(&lcnt[key], 1);
            seg[pos] = v >> BK_SHIFT;
        }
        for (int i = tid; i < ovn; i += 512) {
            int e = ov[i];
            int dst = ei[E + e];
            if ((dst >> BK_SHIFT) == k) {
                int key = dst & BK_MASK;
                int pos = lbeg[key] + atomicAdd(&lcnt[key], 1);
                seg[pos] = ei[e];
            }
        }
        __syncthreads();
        for (int i = tid; i < ecnt; i += 512)
            srclist[ebeg + i] = seg[i];      // coalesced full-line dump
    } else {                                 // fallback for giant buckets
        for (int i = tid; i < nc; i += 512) {
            int v = bk[i];
            int key = v & BK_MASK;
            int pos = lbeg[key] + atomicAdd(&lcnt[key], 1);
            srclist[ebeg + pos] = v >> BK_SHIFT;
        }
        for (int i = tid; i < ovn; i += 512) {
            int e = ov[i];
            int dst = ei[E + e];
            if ((dst >> BK_SHIFT) == k) {
                int key = dst & BK_MASK;
                int pos = lbeg[key] + atomicAdd(&lcnt[key], 1);
                srclist[ebeg + pos] = ei[e];
            }
        }
    }
    __syncthreads();
    int dg = 0;
    if (tid < nn) {
        dg = lcnt[tid];                      // cursor end == degree
        cnt[nd0 + tid] = dg;
        beg[nd0 + tid] = ebeg + lbeg[tid];
    }
    int bin = dg < 63 ? dg : 63;
    if (tid < 64) lh[tid] = 0;
    __syncthreads();
    if (tid < nn) atomicAdd(&lh[bin], 1);
    __syncthreads();
    if (tid < 64) {                          // suffix scan: high bins first
        int cc = lh[tid];
        int pp = cc;
#pragma unroll
        for (int o = 1; o < 64; o <<= 1) {
            int u = __shfl_down(pp, o, 64);
            if (tid + o < 64) pp += u;
        }
        sfx[tid] = pp - cc;
        lh[tid] = 0;                         // reuse as rank cursor
    }
    __syncthreads();
    if (tid < nn) {
        int rank = sfx[bin] + atomicAdd(&lh[bin], 1);   // 0..nn-1 descending
        int pos = (rank < L) ? rank * Bb + k
                             : L * Bb + (rank - L) * (Bb - 1) + k;
        perm[pos] = nd0 + tid;
    }
}

// ---------------- fused SAGE layer: bf16 gather + MFMA combine ----------------
// SAGE IS AT ITS STRUCTURAL FLOOR (~43-47us/layer): 1M random 128B row fetches
// = MSHR/random-granule bound. Evidence: 16 vs 24 waves/CU identical (r10/r12),
// pipelined si issue no change (r17 falsified). Body = round-12/15 measured best.
// Register-cap rule (r1/8/11 spilled): keep (256,3); tighter caps SPILL.
// Spill tripwire: WRITE ~31MB(fp32)/18.7MB(bf16).

__global__ void __launch_bounds__(256, 3) sage_kernel(
    const ushort* __restrict__ inh,      // bf16 rows [N][64]
    const int* __restrict__ perm,
    const int* __restrict__ beg_, const int* __restrict__ cnt_,
    const int* __restrict__ srclist,
    const float* __restrict__ Wl, const float* __restrict__ bl,
    const float* __restrict__ Wr,
    float* __restrict__ out_f32,         // fp32 out (layer 2) or null
    ushort* __restrict__ out_bf,         // bf16 out (layer 1) or null
    int N, int relu) {
    __shared__ short8 fL[8][64];   // [c*2+s][lane]: B-frag of Wl^T, col-tile c, k-step s
    __shared__ short8 fR[8][64];
    int tid = threadIdx.x;
    int lane = tid & 63;
    {
        int c = tid >> 6;
        int n = lane & 15;
        int q = lane >> 4;
#pragma unroll
        for (int s = 0; s < 2; ++s) {
            const float* pl = Wl + (c * 16 + n) * D + s * 32 + q * 8;
            const float* pr = Wr + (c * 16 + n) * D + s * 32 + q * 8;
            short8 vl, vr;
#pragma unroll
            for (int j = 0; j < 8; ++j) {
                vl[j] = (short)f2bf(pl[j]);
                vr[j] = (short)f2bf(pr[j]);
            }
            fL[c * 2 + s][lane] = vl;
            fR[c * 2 + s][lane] = vr;
        }
    }
    __syncthreads();

    int m = lane & 15;
    int q = lane >> 4;
    float b0 = bl[m], b1 = bl[16 + m], b2 = bl[32 + m], b3 = bl[48 + m];
    int gwave   = blockIdx.x * 4 + (tid >> 6);
    int nwaves  = gridDim.x * 4;
    int ngroups = (N + 15) >> 4;

    for (int g = gwave; g < ngroups; g += nwaves) {
        int base = g * 16;
        bool nv = (base + m) < N;
        int node = nv ? perm[base + m] : 0;
        int beg = nv ? beg_[node] : 0;   // 4 lanes per node share the address
        int deg = nv ? cnt_[node] : 0;

        // wave-max degree (uniform under rank-major perm)
        int md = deg;
        md = max(md, __shfl_xor(md, 1, 64));
        md = max(md, __shfl_xor(md, 2, 64));
        md = max(md, __shfl_xor(md, 4, 64));
        md = max(md, __shfl_xor(md, 8, 64));

        float f0[8], f1[8];
#pragma unroll
        for (int u = 0; u < 8; ++u) { f0[u] = 0.f; f1[u] = 0.f; }

        // batched gather: 4 hops per stage -> 8 parallel row loads in flight
        for (int j = 0; j < md; j += 4) {
            int si0, si1, si2, si3;
            {
                int j0 = j,     i0 = beg + ((j0 < deg) ? j0 : 0);
                int j1 = j + 1, i1 = beg + ((j1 < deg) ? j1 : 0);
                int j2 = j + 2, i2 = beg + ((j2 < deg) ? j2 : 0);
                int j3 = j + 3, i3 = beg + ((j3 < deg) ? j3 : 0);
                si0 = srclist[i0]; si1 = srclist[i1];
                si2 = srclist[i2]; si3 = srclist[i3];
            }
            const ushort* rp0 = inh + (size_t)si0 * D;
            const ushort* rp1 = inh + (size_t)si1 * D;
            const ushort* rp2 = inh + (size_t)si2 * D;
            const ushort* rp3 = inh + (size_t)si3 * D;
            short8 lo0 = *(const short8*)(rp0 + q * 8);
            short8 hi0 = *(const short8*)(rp0 + 32 + q * 8);
            short8 lo1 = *(const short8*)(rp1 + q * 8);
            short8 hi1 = *(const short8*)(rp1 + 32 + q * 8);
            short8 lo2 = *(const short8*)(rp2 + q * 8);
            short8 hi2 = *(const short8*)(rp2 + 32 + q * 8);
            short8 lo3 = *(const short8*)(rp3 + q * 8);
            short8 hi3 = *(const short8*)(rp3 + 32 + q * 8);
            float m0 = (j     < deg) ? 1.f : 0.f;
            float m1 = (j + 1 < deg) ? 1.f : 0.f;
            float m2 = (j + 2 < deg) ? 1.f : 0.f;
            float m3 = (j + 3 < deg) ? 1.f : 0.f;
#pragma unroll
            for (int u = 0; u < 8; ++u) {
                f0[u] = fmaf(m0, bf2f((ushort)lo0[u]), f0[u]);
                f1[u] = fmaf(m0, bf2f((ushort)hi0[u]), f1[u]);
                f0[u] = fmaf(m1, bf2f((ushort)lo1[u]), f0[u]);
                f1[u] = fmaf(m1, bf2f((ushort)hi1[u]), f1[u]);
                f0[u] = fmaf(m2, bf2f((ushort)lo2[u]), f0[u]);
                f1[u] = fmaf(m2, bf2f((ushort)hi2[u]), f1[u]);
                f0[u] = fmaf(m3, bf2f((ushort)lo3[u]), f0[u]);
                f1[u] = fmaf(m3, bf2f((ushort)hi3[u]), f1[u]);
            }
        }

        float scale = (deg > 0) ? 1.0f / (float)deg : 0.0f;
        short8 a0, a1;
#pragma unroll
        for (int u = 0; u < 8; ++u) {
            a0[u] = (short)f2bf(f0[u] * scale);
            a1[u] = (short)f2bf(f1[u] * scale);
        }

        // root rows load directly as A-fragments
        const ushort* rr = inh + (size_t)node * D;
        short8 r0 = *(const short8*)(rr + q * 8);
        short8 r1 = *(const short8*)(rr + 32 + q * 8);

        // output nodes of my 4 rows (q*4 + r)
        int on0 = __shfl(node, q * 4 + 0, 64);
        int on1 = __shfl(node, q * 4 + 1, 64);
        int on2 = __shfl(node, q * 4 + 2, 64);
        int on3 = __shfl(node, q * 4 + 3, 64);
        bool v0 = (base + q * 4 + 0) < N;
        bool v1 = (base + q * 4 + 1) < N;
        bool v2 = (base + q * 4 + 2) < N;
        bool v3 = (base + q * 4 + 3) < N;

#pragma unroll
        for (int c = 0; c < 4; ++c) {
            float bc = (c == 0) ? b0 : (c == 1) ? b1 : (c == 2) ? b2 : b3;
            floatx4 acc = {bc, bc, bc, bc};
            acc = __builtin_amdgcn_mfma_f32_16x16x32_bf16(a0, fL[c * 2 + 0][lane], acc, 0, 0, 0);
            acc = __builtin_amdgcn_mfma_f32_16x16x32_bf16(a1, fL[c * 2 + 1][lane], acc, 0, 0, 0);
            acc = __builtin_amdgcn_mfma_f32_16x16x32_bf16(r0, fR[c * 2 + 0][lane], acc, 0, 0, 0);
            acc = __builtin_amdgcn_mfma_f32_16x16x32_bf16(r1, fR[c * 2 + 1][lane], acc, 0, 0, 0);
            // direct stores: 16 lanes x consecutive m = 32B (bf16) / 64B (fp32)
            // aligned sector-complete chunks -> no RMW, no LDS staging.
#pragma unroll
            for (int r = 0; r < 4; ++r) {
                float v = acc[r];
                if (relu) v = fmaxf(v, 0.f);
                int onr = (r == 0) ? on0 : (r == 1) ? on1 : (r == 2) ? on2 : on3;
                bool vr = (r == 0) ? v0 : (r == 1) ? v1 : (r == 2) ? v2 : v3;
                if (vr) {
                    size_t off = (size_t)onr * D + c * 16 + m;
                    if (out_bf) out_bf[off] = f2bf(v);
                    else        out_f32[off] = v;
                }
            }
        }
    }
}

extern "C" void kernel_launch(void* const* d_in, const int* in_sizes, int n_in,
                              void* d_out, int out_size, void* d_ws, size_t ws_size,
                              hipStream_t stream) {
    const float* x   = (const float*)d_in[0];
    const int*   ei  = (const int*)d_in[1];
    const float* W1l = (const float*)d_in[2];
    const float* b1l = (const float*)d_in[3];
    const float* W1r = (const float*)d_in[4];
    const float* W2l = (const float*)d_in[5];
    const float* b2l = (const float*)d_in[6];
    const float* W2r = (const float*)d_in[7];
    float* out = (float*)d_out;

    int N = in_sizes[0] / D;   // 100000
    int E = in_sizes[1] / 2;   // 1000000
    int B = (N + BK_MASK) >> BK_SHIFT;   // 391 buckets
    int eslices = (E + ESLICE - 1) / ESLICE;   // 245

    char* ws = (char*)d_ws;
    // Layout (ints unless noted):
    //   xh  bf16 N*D      hh bf16 N*D      srclist E+64
    //   beg N   cnt N   perm N
    //   bkcur 512 + ovn 1 + pad 3  (one memset clears these 516)
    //   ov E                 (overflow edge indices, rare-path)
    //   bucketed2 B*CAP      (slack-strided bucket regions, ~12.8MB)
    ushort* xh = (ushort*)ws;
    ushort* hh = xh + (size_t)N * D;
    int*   srclist  = (int*)(ws + (size_t)2 * N * D * 2); // E ints + 64 slack
    int*   beg      = srclist + E + 64;                   // N ints
    int*   cnt      = beg + N;                            // N ints
    int*   perm     = cnt + N;                            // N ints
    int*   bkcur    = perm + N;                           // 512 ints (memset)
    int*   ovn      = bkcur + 512;                        // 1 int (memset)
    int*   ov       = ovn + 4;                            // E ints
    int*   bucketed2 = ov + E;                            // B*CAP ints

    (void)hipMemsetAsync(bkcur, 0, 516 * sizeof(int), stream);

    int n4 = N * D / 4;
    int castb = (n4 + 255) / 256;
    cast_route_kernel<<<eslices + castb, 256, 0, stream>>>(x, xh, ei, bkcur, ovn, ov,
                                                           bucketed2, n4, E, B, eslices);
    csr_kernel<<<B, 512, 0, stream>>>(bucketed2, ei, bkcur, ov, ovn,
                                      srclist, beg, cnt, perm, N, E);

    int ngroups = (N + 15) / 16;              // 6250
    int sblocks = (ngroups + 3) / 4;          // 1 group per wave, HW backfill
    // layer 1: hh(bf16) = relu(mean_agg(xh)@W1l^T + b1l + xh@W1r^T)
    sage_kernel<<<sblocks, 256, 0, stream>>>(xh, perm, beg, cnt, srclist,
                                             W1l, b1l, W1r, nullptr, hh, N, 1);
    // layer 2: out(fp32) = mean_agg(hh)@W2l^T + b2l + hh@W2r^T
    sage_kernel<<<sblocks, 256, 0, stream>>>(hh, perm, beg, cnt, srclist,
                                             W2l, b2l, W2r, out, nullptr, N, 0);
}

// Round 21
// 194.990 us; speedup vs baseline: 1.1053x; 1.0097x over previous
//
#include <hip/hip_runtime.h>

#define D 64
#define BK_SHIFT 8
#define BK_MASK 255
#define SEGCAP 4096
#define ESLICE 4096
#define CAP 8192   // slack-strided bucket capacity (mean fill 2560; 30 sigma)

typedef __attribute__((ext_vector_type(8))) short short8;   // 8 bf16 = 4 VGPRs
typedef __attribute__((ext_vector_type(4))) float floatx4;  // MFMA C/D

__device__ __forceinline__ ushort f2bf(float f) {     // fp32 -> bf16, RNE
    unsigned u = __float_as_uint(f);
    u += 0x7fffu + ((u >> 16) & 1u);
    return (ushort)(u >> 16);
}
__device__ __forceinline__ float bf2f(ushort h) {
    return __int_as_float(((unsigned)h) << 16);
}

// ---------------- fused: edge route (blocks < eslices) + cast (rest) --------------
// Round-21: 512 THREADS/BLOCK (same lever that won on csr in round 20).
// Edge role: per-pass serial iterations 16 -> 8; slice size and per-(block,
// bucket) write-run lengths UNCHANGED (round-18 lesson: don't fragment the
// placement runs). Cast role: 1 float4/thread. Slack-strided buckets, no
// count pass, no bucketed2 pre-memset (round-19's 0xFF variant regressed).
__global__ void cast_route_kernel(const float* __restrict__ x, ushort* __restrict__ xh,
                                  const int* __restrict__ ei, int* __restrict__ bkcur,
                                  int* __restrict__ ovn, int* __restrict__ ov,
                                  int* __restrict__ bucketed2,
                                  int n4, int E, int B, int eslices) {
    int bid = blockIdx.x;
    int tid = threadIdx.x;                   // 0..511
    if (bid >= eslices) {                    // ---- cast role
        int i = (bid - eslices) * 512 + tid;
        if (i >= n4) return;
        float4 v = ((const float4*)x)[i];
        ushort4 r;
        r.x = f2bf(v.x); r.y = f2bf(v.y); r.z = f2bf(v.z); r.w = f2bf(v.w);
        ((ushort4*)xh)[i] = r;
        return;
    }
    // ---- edge role: LDS hist -> reserve -> place (8 iters/pass at 512 wide)
    __shared__ int h[512];
    __shared__ int gb[512];
    h[tid] = 0;
    __syncthreads();
    int e0 = bid * ESLICE;
#pragma unroll 4
    for (int it = 0; it < ESLICE / 512; ++it) {      // pass 1: local hist
        int e = e0 + it * 512 + tid;
        if (e < E) atomicAdd(&h[ei[E + e] >> BK_SHIFT], 1);
    }
    __syncthreads();
    gb[tid] = (tid < B && h[tid]) ? atomicAdd(&bkcur[tid], h[tid]) : 0;
    __syncthreads();
    h[tid] = 0;                                      // reuse as cursors
    __syncthreads();
#pragma unroll 4
    for (int it = 0; it < ESLICE / 512; ++it) {      // pass 2: place (dst L2-hot)
        int e = e0 + it * 512 + tid;
        if (e < E) {
            int dst = ei[E + e];
            int key = dst >> BK_SHIFT;
            int src = ei[e];
            int r = atomicAdd(&h[key], 1);
            int pos = gb[key] + r;
            if (pos < CAP) bucketed2[(size_t)key * CAP + pos] = (src << BK_SHIFT) | (dst & BK_MASK);
            else           ov[atomicAdd(ovn, 1)] = e;          // rare overflow
        }
    }
}

// ---------------- B: per-bucket CSR build + RANK-MAJOR degree perm ----------------
// 512 threads/block (round-20 win): halves per-entry loop trip counts without
// touching route. Dense srclist offsets via block-redundant 512-scan of clamped
// bkcur (+ overflow). perm rank-major: local descending rank r in bucket k ->
// perm[r*B + k] (compacted partial last bucket).
__global__ void csr_kernel(const int* __restrict__ bucketed2, const int* __restrict__ ei,
                           const int* __restrict__ bkcur, const int* __restrict__ ov,
                           const int* __restrict__ ovn_p,
                           int* __restrict__ srclist, int* __restrict__ beg,
                           int* __restrict__ cnt, int* __restrict__ perm, int N, int E) {
    __shared__ int btot[512];
    __shared__ int lcnt[256];
    __shared__ int lbeg[256];
    __shared__ int seg[SEGCAP];
    __shared__ int wsum[8];
    __shared__ int lh[64];
    __shared__ int sfx[64];
    int k = blockIdx.x;
    int Bb = gridDim.x;
    int tid = threadIdx.x;                   // 0..511
    int nd0 = k << BK_SHIFT;
    int nn = min(256, N - nd0);
    int L = N - (Bb - 1) * 256;              // last-bucket size (1..256)
    int ovn = *ovn_p;
    btot[tid] = (tid < Bb) ? min(bkcur[tid], CAP) : 0;
    __syncthreads();
    for (int i = tid; i < ovn; i += 512)     // rare: add overflow to totals
        atomicAdd(&btot[ei[E + ov[i]] >> BK_SHIFT], 1);
    __syncthreads();
    int nc   = min(bkcur[k], CAP);           // entries in my bucket region
    int ecnt = btot[k];                      // incl. overflow
    int a = btot[tid];                       // 1 elem/thread (512-wide)
    __syncthreads();
    // exclusive 512-scan of btot (8 waves)
    int lane = tid & 63, w = tid >> 6;
    int p = a;
#pragma unroll
    for (int o = 1; o < 64; o <<= 1) {
        int u = __shfl_up(p, o, 64);
        if (lane >= o) p += u;
    }
    if (lane == 63) wsum[w] = p;
    __syncthreads();
    int base = 0;
    for (int ww = 0; ww < w; ++ww) base += wsum[ww];
    btot[tid] = base + p - a;                // exclusive prefix
    if (tid < 256) lcnt[tid] = 0;
    __syncthreads();
    int ebeg = btot[k];                      // dense srclist base of bucket k
    const int* bk = bucketed2 + (size_t)k * CAP;
    for (int i = tid; i < nc; i += 512)      // degree count
        atomicAdd(&lcnt[bk[i] & BK_MASK], 1);
    for (int i = tid; i < ovn; i += 512) {   // rare overflow contribution
        int dst = ei[E + ov[i]];
        if ((dst >> BK_SHIFT) == k) atomicAdd(&lcnt[dst & BK_MASK], 1);
    }
    __syncthreads();
    // exclusive 256-scan of lcnt (first 4 waves)
    int c = (tid < 256) ? lcnt[tid] : 0;
    p = c;
#pragma unroll
    for (int o = 1; o < 64; o <<= 1) {
        int u = __shfl_up(p, o, 64);
        if (lane >= o) p += u;
    }
    if (lane == 63 && tid < 256) wsum[w] = p;
    __syncthreads();
    if (tid < 256) {
        base = 0;
        for (int ww = 0; ww < w; ++ww) base += wsum[ww];
        lbeg[tid] = base + p - c;
        lcnt[tid] = 0;                       // reuse as fill cursors
    }
    __syncthreads();
    if (ecnt <= SEGCAP) {
        for (int i = tid; i < nc; i += 512) {
            int v = bk[i];
            int key = v & BK_MASK;
            int pos = lbeg[key] + atomicAdd(&lcnt[key], 1);
            seg[pos] = v >> BK_SHIFT;
        }
        for (int i = tid; i < ovn; i += 512) {
            int e = ov[i];
            int dst = ei[E + e];
            if ((dst >> BK_SHIFT) == k) {
                int key = dst & BK_MASK;
                int pos = lbeg[key] + atomicAdd(&lcnt[key], 1);
                seg[pos] = ei[e];
            }
        }
        __syncthreads();
        for (int i = tid; i < ecnt; i += 512)
            srclist[ebeg + i] = seg[i];      // coalesced full-line dump
    } else {                                 // fallback for giant buckets
        for (int i = tid; i < nc; i += 512) {
            int v = bk[i];
            int key = v & BK_MASK;
            int pos = lbeg[key] + atomicAdd(&lcnt[key], 1);
            srclist[ebeg + pos] = v >> BK_SHIFT;
        }
        for (int i = tid; i < ovn; i += 512) {
            int e = ov[i];
            int dst = ei[E + e];
            if ((dst >> BK_SHIFT) == k) {
                int key = dst & BK_MASK;
                int pos = lbeg[key] + atomicAdd(&lcnt[key], 1);
                srclist[ebeg + pos] = ei[e];
            }
        }
    }
    __syncthreads();
    int dg = 0;
    if (tid < nn) {
        dg = lcnt[tid];                      // cursor end == degree
        cnt[nd0 + tid] = dg;
        beg[nd0 + tid] = ebeg + lbeg[tid];
    }
    int bin = dg < 63 ? dg : 63;
    if (tid < 64) lh[tid] = 0;
    __syncthreads();
    if (tid < nn) atomicAdd(&lh[bin], 1);
    __syncthreads();
    if (tid < 64) {                          // suffix scan: high bins first
        int cc = lh[tid];
        int pp = cc;
#pragma unroll
        for (int o = 1; o < 64; o <<= 1) {
            int u = __shfl_down(pp, o, 64);
            if (tid + o < 64) pp += u;
        }
        sfx[tid] = pp - cc;
        lh[tid] = 0;                         // reuse as rank cursor
    }
    __syncthreads();
    if (tid < nn) {
        int rank = sfx[bin] + atomicAdd(&lh[bin], 1);   // 0..nn-1 descending
        int pos = (rank < L) ? rank * Bb + k
                             : L * Bb + (rank - L) * (Bb - 1) + k;
        perm[pos] = nd0 + tid;
    }
}

// ---------------- fused SAGE layer: bf16 gather + MFMA combine ----------------
// SAGE IS AT ITS STRUCTURAL FLOOR (~43-47us/layer): 1M random 128B row fetches
// = MSHR/random-granule bound. Evidence: 16 vs 24 waves/CU identical (r10/r12),
// pipelined si issue no change (r17 falsified). Body = round-12/15 measured best.
// Register-cap rule (r1/8/11 spilled): keep (256,3); tighter caps SPILL.
// Spill tripwire: WRITE ~31MB(fp32)/18.7MB(bf16).

__global__ void __launch_bounds__(256, 3) sage_kernel(
    const ushort* __restrict__ inh,      // bf16 rows [N][64]
    const int* __restrict__ perm,
    const int* __restrict__ beg_, const int* __restrict__ cnt_,
    const int* __restrict__ srclist,
    const float* __restrict__ Wl, const float* __restrict__ bl,
    const float* __restrict__ Wr,
    float* __restrict__ out_f32,         // fp32 out (layer 2) or null
    ushort* __restrict__ out_bf,         // bf16 out (layer 1) or null
    int N, int relu) {
    __shared__ short8 fL[8][64];   // [c*2+s][lane]: B-frag of Wl^T, col-tile c, k-step s
    __shared__ short8 fR[8][64];
    int tid = threadIdx.x;
    int lane = tid & 63;
    {
        int c = tid >> 6;
        int n = lane & 15;
        int q = lane >> 4;
#pragma unroll
        for (int s = 0; s < 2; ++s) {
            const float* pl = Wl + (c * 16 + n) * D + s * 32 + q * 8;
            const float* pr = Wr + (c * 16 + n) * D + s * 32 + q * 8;
            short8 vl, vr;
#pragma unroll
            for (int j = 0; j < 8; ++j) {
                vl[j] = (short)f2bf(pl[j]);
                vr[j] = (short)f2bf(pr[j]);
            }
            fL[c * 2 + s][lane] = vl;
            fR[c * 2 + s][lane] = vr;
        }
    }
    __syncthreads();

    int m = lane & 15;
    int q = lane >> 4;
    float b0 = bl[m], b1 = bl[16 + m], b2 = bl[32 + m], b3 = bl[48 + m];
    int gwave   = blockIdx.x * 4 + (tid >> 6);
    int nwaves  = gridDim.x * 4;
    int ngroups = (N + 15) >> 4;

    for (int g = gwave; g < ngroups; g += nwaves) {
        int base = g * 16;
        bool nv = (base + m) < N;
        int node = nv ? perm[base + m] : 0;
        int beg = nv ? beg_[node] : 0;   // 4 lanes per node share the address
        int deg = nv ? cnt_[node] : 0;

        // wave-max degree (uniform under rank-major perm)
        int md = deg;
        md = max(md, __shfl_xor(md, 1, 64));
        md = max(md, __shfl_xor(md, 2, 64));
        md = max(md, __shfl_xor(md, 4, 64));
        md = max(md, __shfl_xor(md, 8, 64));

        float f0[8], f1[8];
#pragma unroll
        for (int u = 0; u < 8; ++u) { f0[u] = 0.f; f1[u] = 0.f; }

        // batched gather: 4 hops per stage -> 8 parallel row loads in flight
        for (int j = 0; j < md; j += 4) {
            int si0, si1, si2, si3;
            {
                int j0 = j,     i0 = beg + ((j0 < deg) ? j0 : 0);
                int j1 = j + 1, i1 = beg + ((j1 < deg) ? j1 : 0);
                int j2 = j + 2, i2 = beg + ((j2 < deg) ? j2 : 0);
                int j3 = j + 3, i3 = beg + ((j3 < deg) ? j3 : 0);
                si0 = srclist[i0]; si1 = srclist[i1];
                si2 = srclist[i2]; si3 = srclist[i3];
            }
            const ushort* rp0 = inh + (size_t)si0 * D;
            const ushort* rp1 = inh + (size_t)si1 * D;
            const ushort* rp2 = inh + (size_t)si2 * D;
            const ushort* rp3 = inh + (size_t)si3 * D;
            short8 lo0 = *(const short8*)(rp0 + q * 8);
            short8 hi0 = *(const short8*)(rp0 + 32 + q * 8);
            short8 lo1 = *(const short8*)(rp1 + q * 8);
            short8 hi1 = *(const short8*)(rp1 + 32 + q * 8);
            short8 lo2 = *(const short8*)(rp2 + q * 8);
            short8 hi2 = *(const short8*)(rp2 + 32 + q * 8);
            short8 lo3 = *(const short8*)(rp3 + q * 8);
            short8 hi3 = *(const short8*)(rp3 + 32 + q * 8);
            float m0 = (j     < deg) ? 1.f : 0.f;
            float m1 = (j + 1 < deg) ? 1.f : 0.f;
            float m2 = (j + 2 < deg) ? 1.f : 0.f;
            float m3 = (j + 3 < deg) ? 1.f : 0.f;
#pragma unroll
            for (int u = 0; u < 8; ++u) {
                f0[u] = fmaf(m0, bf2f((ushort)lo0[u]), f0[u]);
                f1[u] = fmaf(m0, bf2f((ushort)hi0[u]), f1[u]);
                f0[u] = fmaf(m1, bf2f((ushort)lo1[u]), f0[u]);
                f1[u] = fmaf(m1, bf2f((ushort)hi1[u]), f1[u]);
                f0[u] = fmaf(m2, bf2f((ushort)lo2[u]), f0[u]);
                f1[u] = fmaf(m2, bf2f((ushort)hi2[u]), f1[u]);
                f0[u] = fmaf(m3, bf2f((ushort)lo3[u]), f0[u]);
                f1[u] = fmaf(m3, bf2f((ushort)hi3[u]), f1[u]);
            }
        }

        float scale = (deg > 0) ? 1.0f / (float)deg : 0.0f;
        short8 a0, a1;
#pragma unroll
        for (int u = 0; u < 8; ++u) {
            a0[u] = (short)f2bf(f0[u] * scale);
            a1[u] = (short)f2bf(f1[u] * scale);
        }

        // root rows load directly as A-fragments
        const ushort* rr = inh + (size_t)node * D;
        short8 r0 = *(const short8*)(rr + q * 8);
        short8 r1 = *(const short8*)(rr + 32 + q * 8);

        // output nodes of my 4 rows (q*4 + r)
        int on0 = __shfl(node, q * 4 + 0, 64);
        int on1 = __shfl(node, q * 4 + 1, 64);
        int on2 = __shfl(node, q * 4 + 2, 64);
        int on3 = __shfl(node, q * 4 + 3, 64);
        bool v0 = (base + q * 4 + 0) < N;
        bool v1 = (base + q * 4 + 1) < N;
        bool v2 = (base + q * 4 + 2) < N;
        bool v3 = (base + q * 4 + 3) < N;

#pragma unroll
        for (int c = 0; c < 4; ++c) {
            float bc = (c == 0) ? b0 : (c == 1) ? b1 : (c == 2) ? b2 : b3;
            floatx4 acc = {bc, bc, bc, bc};
            acc = __builtin_amdgcn_mfma_f32_16x16x32_bf16(a0, fL[c * 2 + 0][lane], acc, 0, 0, 0);
            acc = __builtin_amdgcn_mfma_f32_16x16x32_bf16(a1, fL[c * 2 + 1][lane], acc, 0, 0, 0);
            acc = __builtin_amdgcn_mfma_f32_16x16x32_bf16(r0, fR[c * 2 + 0][lane], acc, 0, 0, 0);
            acc = __builtin_amdgcn_mfma_f32_16x16x32_bf16(r1, fR[c * 2 + 1][lane], acc, 0, 0, 0);
            // direct stores: 16 lanes x consecutive m = 32B (bf16) / 64B (fp32)
            // aligned sector-complete chunks -> no RMW, no LDS staging.
#pragma unroll
            for (int r = 0; r < 4; ++r) {
                float v = acc[r];
                if (relu) v = fmaxf(v, 0.f);
                int onr = (r == 0) ? on0 : (r == 1) ? on1 : (r == 2) ? on2 : on3;
                bool vr = (r == 0) ? v0 : (r == 1) ? v1 : (r == 2) ? v2 : v3;
                if (vr) {
                    size_t off = (size_t)onr * D + c * 16 + m;
                    if (out_bf) out_bf[off] = f2bf(v);
                    else        out_f32[off] = v;
                }
            }
        }
    }
}

extern "C" void kernel_launch(void* const* d_in, const int* in_sizes, int n_in,
                              void* d_out, int out_size, void* d_ws, size_t ws_size,
                              hipStream_t stream) {
    const float* x   = (const float*)d_in[0];
    const int*   ei  = (const int*)d_in[1];
    const float* W1l = (const float*)d_in[2];
    const float* b1l = (const float*)d_in[3];
    const float* W1r = (const float*)d_in[4];
    const float* W2l = (const float*)d_in[5];
    const float* b2l = (const float*)d_in[6];
    const float* W2r = (const float*)d_in[7];
    float* out = (float*)d_out;

    int N = in_sizes[0] / D;   // 100000
    int E = in_sizes[1] / 2;   // 1000000
    int B = (N + BK_MASK) >> BK_SHIFT;   // 391 buckets
    int eslices = (E + ESLICE - 1) / ESLICE;   // 245

    char* ws = (char*)d_ws;
    // Layout (ints unless noted):
    //   xh  bf16 N*D      hh bf16 N*D      srclist E+64
    //   beg N   cnt N   perm N
    //   bkcur 512 + ovn 1 + pad 3  (one memset clears these 516)
    //   ov E                 (overflow edge indices, rare-path)
    //   bucketed2 B*CAP      (slack-strided bucket regions, ~12.8MB)
    ushort* xh = (ushort*)ws;
    ushort* hh = xh + (size_t)N * D;
    int*   srclist  = (int*)(ws + (size_t)2 * N * D * 2); // E ints + 64 slack
    int*   beg      = srclist + E + 64;                   // N ints
    int*   cnt      = beg + N;                            // N ints
    int*   perm     = cnt + N;                            // N ints
    int*   bkcur    = perm + N;                           // 512 ints (memset)
    int*   ovn      = bkcur + 512;                        // 1 int (memset)
    int*   ov       = ovn + 4;                            // E ints
    int*   bucketed2 = ov + E;                            // B*CAP ints

    (void)hipMemsetAsync(bkcur, 0, 516 * sizeof(int), stream);

    int n4 = N * D / 4;
    int castb = (n4 + 511) / 512;             // 3125 cast blocks at 512 thr
    cast_route_kernel<<<eslices + castb, 512, 0, stream>>>(x, xh, ei, bkcur, ovn, ov,
                                                           bucketed2, n4, E, B, eslices);
    csr_kernel<<<B, 512, 0, stream>>>(bucketed2, ei, bkcur, ov, ovn,
                                      srclist, beg, cnt, perm, N, E);

    int ngroups = (N + 15) / 16;              // 6250
    int sblocks = (ngroups + 3) / 4;          // 1 group per wave, HW backfill
    // layer 1: hh(bf16) = relu(mean_agg(xh)@W1l^T + b1l + xh@W1r^T)
    sage_kernel<<<sblocks, 256, 0, stream>>>(xh, perm, beg, cnt, srclist,
                                             W1l, b1l, W1r, nullptr, hh, N, 1);
    // layer 2: out(fp32) = mean_agg(hh)@W2l^T + b2l + hh@W2r^T
    sage_kernel<<<sblocks, 256, 0, stream>>>(hh, perm, beg, cnt, srclist,
                                             W2l, b2l, W2r, out, nullptr, N, 0);
}